// Round 7
// baseline (190.395 us; speedup 1.0000x reference)
//
#include <hip/hip_runtime.h>

// ROI Align on MI355X.
// input: (N=8, C=256, H=100, W=100) fp32 NCHW; rois (K,5); out (K,256,7,7) fp32.
//
// Round 7: round-5/6 established: fp32 gather was bytes-bound at the ~3.4TB/s
// scattered-service ceiling (occupancy didn't matter); bf16 halved bytes and
// dropped below that ceiling (2.4TB/s, Occ 20.5%) -> now latency-bound.
// Fix parallelism without adding loads: block = (ROI, bin-half 25/24), full
// 256-ch uint2 corner loads (512B/wave, line-dense), LDS output staged as
// bf16 (12.8KB -> no LDS occupancy cap, ~31 waves/CU grid-limited).

typedef float nfloat4 __attribute__((ext_vector_type(4)));

constexpr int   OUT_H = 7;
constexpr int   OUT_W = 7;
constexpr int   NBINS = OUT_H * OUT_W;          // 49
constexpr int   NB_MAX = 25;                    // bins per half (25 / 24)
constexpr float SPATIAL_SCALE = 0.25f;
constexpr int   SR = 2;
constexpr int   N_DIM = 8;
constexpr int   C_DIM = 256;
constexpr int   H_DIM = 100;
constexpr int   W_DIM = 100;
constexpr int   HW    = H_DIM * W_DIM;          // 10000
constexpr size_t NHWC_BF16_BYTES = (size_t)N_DIM * HW * C_DIM * 2; // 40,960,000

__device__ inline unsigned short f2bf_rne(float f) {
    unsigned u = __float_as_uint(f);
    u += 0x7fffu + ((u >> 16) & 1u);    // round-to-nearest-even
    return (unsigned short)(u >> 16);
}

// ---------------- transpose+cast: NCHW fp32 -> NHWC bf16 --------------------
// Tile 64ch x 64sp. Global float4 in / ushort4 out; LDS fp32 stride 65
// (bank = (c+s)%32 both sides -> <=2-way, free).
constexpr int TP = 65;

__global__ __launch_bounds__(256) void nchw_to_nhwc_bf16(
    const float* __restrict__ in, unsigned short* __restrict__ out)
{
    __shared__ float tile[64 * TP];    // 16640 B
    int s0 = blockIdx.x * 64;
    int c0 = blockIdx.y * 64;
    int n  = blockIdx.z;

    int t   = threadIdx.x;
    int sl4 = (t & 15) * 4;
    int cq  = t >> 4;                  // 0..15

    #pragma unroll
    for (int r = 0; r < 4; ++r) {
        int cl = r * 16 + cq;
        int s  = s0 + sl4;
        const float* src = in + ((size_t)(n * C_DIM + c0 + cl) * HW + s);
        if (s + 3 < HW) {
            float4 v = *(const float4*)src;
            tile[cl * TP + sl4 + 0] = v.x;
            tile[cl * TP + sl4 + 1] = v.y;
            tile[cl * TP + sl4 + 2] = v.z;
            tile[cl * TP + sl4 + 3] = v.w;
        } else {
            #pragma unroll
            for (int i = 0; i < 4; ++i)
                tile[cl * TP + sl4 + i] = (s + i < HW) ? src[i] : 0.0f;
        }
    }
    __syncthreads();

    int cl4 = (t & 15) * 4;
    #pragma unroll
    for (int r = 0; r < 4; ++r) {
        int sl = r * 16 + cq;
        int s  = s0 + sl;
        if (s < HW) {
            ushort4 h;
            h.x = f2bf_rne(tile[(cl4 + 0) * TP + sl]);
            h.y = f2bf_rne(tile[(cl4 + 1) * TP + sl]);
            h.z = f2bf_rne(tile[(cl4 + 2) * TP + sl]);
            h.w = f2bf_rne(tile[(cl4 + 3) * TP + sl]);
            *(ushort4*)(out + ((size_t)n * HW + s) * C_DIM + c0 + cl4) = h;
        }
    }
}

// ---------------- gather: block = (ROI, bin-half), lane = 4 bf16 channels ----
__global__ __launch_bounds__(256) void roi_gather_nhwc_bf16(
    const unsigned short* __restrict__ nhwc,
    const float* __restrict__ rois,
    float* __restrict__ out, int K)
{
    __shared__ unsigned short s_out[C_DIM * NB_MAX];   // 12800 B

    int k = blockIdx.x;
    int h = blockIdx.y;                    // bin half: 0 -> bins 0..24, 1 -> 25..48
    int bin0  = h * NB_MAX;
    int count = NBINS - bin0 < NB_MAX ? NBINS - bin0 : NB_MAX;   // 25 or 24

    const float* r = rois + (size_t)k * 5;
    int   b  = (int)r[0];
    float x1 = r[1] * SPATIAL_SCALE;
    float y1 = r[2] * SPATIAL_SCALE;
    float x2 = r[3] * SPATIAL_SCALE;
    float y2 = r[4] * SPATIAL_SCALE;
    float roi_w = fmaxf(x2 - x1, 1.0f);
    float roi_h = fmaxf(y2 - y1, 1.0f);
    float bin_h = roi_h / (float)OUT_H;
    float bin_w = roi_w / (float)OUT_W;

    int wave = threadIdx.x >> 6;
    int lane = threadIdx.x & 63;
    int cb   = lane * 4;                   // channel base

    const unsigned short* img = nhwc + (size_t)b * HW * C_DIM;

    for (int bi = wave; bi < count; bi += 4) {
        int bin = bin0 + bi;
        int oh = bin / OUT_W;
        int ow = bin - oh * OUT_W;

        float2 a01 = {0.f, 0.f}, a23 = {0.f, 0.f};

        #pragma unroll
        for (int sy = 0; sy < SR; ++sy) {
            float gy = y1 + bin_h * (((float)(oh * SR + sy) + 0.5f) / (float)SR);
            bool  vy = (gy >= -1.0f) && (gy <= (float)H_DIM);
            float y  = fminf(fmaxf(gy, 0.0f), (float)(H_DIM - 1));
            int   yl = (int)floorf(y);
            float ly = y - (float)yl;
            int   yh = min(yl + 1, H_DIM - 1);

            #pragma unroll
            for (int sx = 0; sx < SR; ++sx) {
                float gx = x1 + bin_w * (((float)(ow * SR + sx) + 0.5f) / (float)SR);
                bool  vx = (gx >= -1.0f) && (gx <= (float)W_DIM);
                float x  = fminf(fmaxf(gx, 0.0f), (float)(W_DIM - 1));
                int   xl = (int)floorf(x);
                float lx = x - (float)xl;
                int   xh = min(xl + 1, W_DIM - 1);

                const uint2 qll = *(const uint2*)(img + (size_t)(yl * W_DIM + xl) * C_DIM + cb);
                const uint2 qlh = *(const uint2*)(img + (size_t)(yl * W_DIM + xh) * C_DIM + cb);
                const uint2 qhl = *(const uint2*)(img + (size_t)(yh * W_DIM + xl) * C_DIM + cb);
                const uint2 qhh = *(const uint2*)(img + (size_t)(yh * W_DIM + xh) * C_DIM + cb);

                float wll = (1.0f - ly) * (1.0f - lx);
                float wlh = (1.0f - ly) * lx;
                float whl = ly * (1.0f - lx);
                float whh = ly * lx;

                if (vy && vx) {
                    #define ACC2(acc, q, w) { \
                        float lo = __uint_as_float((q) << 16); \
                        float hi = __uint_as_float((q) & 0xffff0000u); \
                        acc.x = fmaf((w), lo, acc.x); \
                        acc.y = fmaf((w), hi, acc.y); }
                    ACC2(a01, qll.x, wll) ACC2(a23, qll.y, wll)
                    ACC2(a01, qlh.x, wlh) ACC2(a23, qlh.y, wlh)
                    ACC2(a01, qhl.x, whl) ACC2(a23, qhl.y, whl)
                    ACC2(a01, qhh.x, whh) ACC2(a23, qhh.y, whh)
                    #undef ACC2
                }
            }
        }
        s_out[(cb + 0) * NB_MAX + bi] = f2bf_rne(a01.x * 0.25f);
        s_out[(cb + 1) * NB_MAX + bi] = f2bf_rne(a01.y * 0.25f);
        s_out[(cb + 2) * NB_MAX + bi] = f2bf_rne(a23.x * 0.25f);
        s_out[(cb + 3) * NB_MAX + bi] = f2bf_rne(a23.y * 0.25f);
    }
    __syncthreads();

    // copy-out: 256ch x count bins; out[k][c][bin0 + j], runs of `count` floats
    float* obase = out + (size_t)k * (C_DIM * NBINS) + bin0;
    int total = C_DIM * count;
    for (int i = threadIdx.x; i < total; i += 256) {
        int c = i / count;
        int j = i - c * count;
        unsigned short v = s_out[c * NB_MAX + j];
        obase[c * NBINS + j] = __uint_as_float((unsigned)v << 16);
    }
}

// ---------------- fallback (round-0 baseline) if ws too small ---------------
__global__ __launch_bounds__(256) void roi_align_naive(
    const float* __restrict__ input, const float* __restrict__ rois,
    float* __restrict__ out, int K)
{
    int idx = blockIdx.x * blockDim.x + threadIdx.x;
    int total = K * C_DIM * OUT_H * OUT_W;
    if (idx >= total) return;
    int ow = idx % OUT_W;
    int oh = (idx / OUT_W) % OUT_H;
    int c  = (idx / (OUT_W * OUT_H)) % C_DIM;
    int k  = idx / (OUT_W * OUT_H * C_DIM);
    const float* r = rois + (size_t)k * 5;
    int   b  = (int)r[0];
    float x1 = r[1] * SPATIAL_SCALE, y1 = r[2] * SPATIAL_SCALE;
    float x2 = r[3] * SPATIAL_SCALE, y2 = r[4] * SPATIAL_SCALE;
    float roi_w = fmaxf(x2 - x1, 1.0f), roi_h = fmaxf(y2 - y1, 1.0f);
    float bin_h = roi_h / OUT_H, bin_w = roi_w / OUT_W;
    const float* inp = input + ((size_t)b * C_DIM + c) * HW;
    float acc = 0.0f;
    #pragma unroll
    for (int sy = 0; sy < SR; ++sy) {
        float gy = y1 + bin_h * (((float)(oh * SR + sy) + 0.5f) / SR);
        bool vy = (gy >= -1.0f) && (gy <= (float)H_DIM);
        float y = fminf(fmaxf(gy, 0.0f), (float)(H_DIM - 1));
        int yl = (int)floorf(y); float ly = y - yl; int yh = min(yl + 1, H_DIM - 1);
        #pragma unroll
        for (int sx = 0; sx < SR; ++sx) {
            float gx = x1 + bin_w * (((float)(ow * SR + sx) + 0.5f) / SR);
            bool vx = (gx >= -1.0f) && (gx <= (float)W_DIM);
            float x = fminf(fmaxf(gx, 0.0f), (float)(W_DIM - 1));
            int xl = (int)floorf(x); float lx = x - xl; int xh = min(xl + 1, W_DIM - 1);
            float v = (1.0f - ly) * ((1.0f - lx) * inp[yl * W_DIM + xl] + lx * inp[yl * W_DIM + xh])
                    + ly * ((1.0f - lx) * inp[yh * W_DIM + xl] + lx * inp[yh * W_DIM + xh]);
            if (vy && vx) acc += v;
        }
    }
    out[idx] = acc * 0.25f;
}

extern "C" void kernel_launch(void* const* d_in, const int* in_sizes, int n_in,
                              void* d_out, int out_size, void* d_ws, size_t ws_size,
                              hipStream_t stream) {
    const float* input = (const float*)d_in[0];
    const float* rois  = (const float*)d_in[1];
    float* out = (float*)d_out;
    int K = in_sizes[1] / 5;

    if (ws_size >= NHWC_BF16_BYTES) {
        unsigned short* nhwc = (unsigned short*)d_ws;
        dim3 tgrid((HW + 63) / 64, C_DIM / 64, N_DIM);   // 157 x 4 x 8
        nchw_to_nhwc_bf16<<<tgrid, 256, 0, stream>>>(input, nhwc);
        dim3 ggrid(K, 2);
        roi_gather_nhwc_bf16<<<ggrid, 256, 0, stream>>>(nhwc, rois, out, K);
    } else {
        int total = K * C_DIM * OUT_H * OUT_W;
        roi_align_naive<<<(total + 255) / 256, 256, 0, stream>>>(input, rois, out, K);
    }
}

// Round 8
// 183.606 us; speedup vs baseline: 1.0370x; 1.0370x over previous
//
#include <hip/hip_runtime.h>

// ROI Align on MI355X.
// input: (N=8, C=256, H=100, W=100) fp32 NCHW; rois (K,5); out (K,256,7,7) fp32.
//
// Round 8: r5/r7 proved occupancy is a dead knob; r6/r7 invariant is L2-miss
// volume (~98-114MB vs 4MB/XCD L2: every XCD's working set is the whole 39MB
// NHWC array). Fix: batch->XCD affinity. Tiny bucket kernel builds map[] so
// block k handles a ROI of batch ~= k%8 (round-robin blockIdx->XCD heuristic);
// each XCD then reads mostly one 4.9MB image (fits its L2). Gather = r6 shape.

typedef float nfloat4 __attribute__((ext_vector_type(4)));

constexpr int   OUT_H = 7;
constexpr int   OUT_W = 7;
constexpr int   NBINS = OUT_H * OUT_W;          // 49
constexpr float SPATIAL_SCALE = 0.25f;
constexpr int   SR = 2;
constexpr int   N_DIM = 8;
constexpr int   C_DIM = 256;
constexpr int   H_DIM = 100;
constexpr int   W_DIM = 100;
constexpr int   HW    = H_DIM * W_DIM;          // 10000
constexpr size_t NHWC_BF16_BYTES = (size_t)N_DIM * HW * C_DIM * 2; // 40,960,000
constexpr int   MAX_BUCKET_K = 2048;

__device__ inline unsigned short f2bf_rne(float f) {
    unsigned u = __float_as_uint(f);
    u += 0x7fffu + ((u >> 16) & 1u);    // round-to-nearest-even
    return (unsigned short)(u >> 16);
}

// ---------------- transpose+cast: NCHW fp32 -> NHWC bf16 (unchanged r6) -----
constexpr int TP = 65;

__global__ __launch_bounds__(256) void nchw_to_nhwc_bf16(
    const float* __restrict__ in, unsigned short* __restrict__ out)
{
    __shared__ float tile[64 * TP];    // 16640 B
    int s0 = blockIdx.x * 64;
    int c0 = blockIdx.y * 64;
    int n  = blockIdx.z;

    int t   = threadIdx.x;
    int sl4 = (t & 15) * 4;
    int cq  = t >> 4;                  // 0..15

    #pragma unroll
    for (int r = 0; r < 4; ++r) {
        int cl = r * 16 + cq;
        int s  = s0 + sl4;
        const float* src = in + ((size_t)(n * C_DIM + c0 + cl) * HW + s);
        if (s + 3 < HW) {
            float4 v = *(const float4*)src;
            tile[cl * TP + sl4 + 0] = v.x;
            tile[cl * TP + sl4 + 1] = v.y;
            tile[cl * TP + sl4 + 2] = v.z;
            tile[cl * TP + sl4 + 3] = v.w;
        } else {
            #pragma unroll
            for (int i = 0; i < 4; ++i)
                tile[cl * TP + sl4 + i] = (s + i < HW) ? src[i] : 0.0f;
        }
    }
    __syncthreads();

    int cl4 = (t & 15) * 4;
    #pragma unroll
    for (int r = 0; r < 4; ++r) {
        int sl = r * 16 + cq;
        int s  = s0 + sl;
        if (s < HW) {
            ushort4 h;
            h.x = f2bf_rne(tile[(cl4 + 0) * TP + sl]);
            h.y = f2bf_rne(tile[(cl4 + 1) * TP + sl]);
            h.z = f2bf_rne(tile[(cl4 + 2) * TP + sl]);
            h.w = f2bf_rne(tile[(cl4 + 3) * TP + sl]);
            *(ushort4*)(out + ((size_t)n * HW + s) * C_DIM + c0 + cl4) = h;
        }
    }
}

// ---------------- bucket: map[k] = ROI index with batch ~= k%8 --------------
// Single block. Positions b+8r (r < K/8) get batch b; overflow ROIs fill the
// holes left by underfull batches (~4% misplaced residues, harmless).
__global__ __launch_bounds__(1024) void bucket_by_batch(
    const float* __restrict__ rois, int K, int* __restrict__ map)
{
    __shared__ int cnt[8];
    __shared__ int ovf[MAX_BUCKET_K];
    __shared__ int holes[MAX_BUCKET_K];
    __shared__ int ovfCnt, holeCnt;
    int t = threadIdx.x;
    if (t < 8) cnt[t] = 0;
    if (t == 0) { ovfCnt = 0; holeCnt = 0; }
    for (int i = t; i < K; i += 1024) map[i] = -1;
    __syncthreads();

    int per = K / 8;
    for (int i = t; i < K; i += 1024) {
        int b = ((int)rois[(size_t)i * 5]) & 7;
        int r = atomicAdd(&cnt[b], 1);
        if (r < per) map[b + 8 * r] = i;
        else ovf[atomicAdd(&ovfCnt, 1)] = i;
    }
    __syncthreads();
    for (int i = t; i < K; i += 1024)
        if (map[i] == -1) holes[atomicAdd(&holeCnt, 1)] = i;
    __syncthreads();
    for (int i = t; i < ovfCnt; i += 1024)
        map[holes[i]] = ovf[i];
}

// ---------------- gather: block per ROI (via map), wave/bin, lane=4 bf16 ch -
__global__ __launch_bounds__(256) void roi_gather_nhwc_bf16(
    const unsigned short* __restrict__ nhwc,
    const float* __restrict__ rois,
    const int* __restrict__ map,
    float* __restrict__ out, int K)
{
    __shared__ float s_out[C_DIM * NBINS];   // 50176 B

    int k = map ? map[blockIdx.x] : (int)blockIdx.x;
    const float* r = rois + (size_t)k * 5;
    int   b  = (int)r[0];
    float x1 = r[1] * SPATIAL_SCALE;
    float y1 = r[2] * SPATIAL_SCALE;
    float x2 = r[3] * SPATIAL_SCALE;
    float y2 = r[4] * SPATIAL_SCALE;
    float roi_w = fmaxf(x2 - x1, 1.0f);
    float roi_h = fmaxf(y2 - y1, 1.0f);
    float bin_h = roi_h / (float)OUT_H;
    float bin_w = roi_w / (float)OUT_W;

    int wave = threadIdx.x >> 6;
    int lane = threadIdx.x & 63;
    int cb   = lane * 4;                     // channel base

    const unsigned short* img = nhwc + (size_t)b * HW * C_DIM;

    for (int bin = wave; bin < NBINS; bin += 4) {
        int oh = bin / OUT_W;
        int ow = bin - oh * OUT_W;

        float2 a01 = {0.f, 0.f}, a23 = {0.f, 0.f};

        #pragma unroll
        for (int sy = 0; sy < SR; ++sy) {
            float gy = y1 + bin_h * (((float)(oh * SR + sy) + 0.5f) / (float)SR);
            bool  vy = (gy >= -1.0f) && (gy <= (float)H_DIM);
            float y  = fminf(fmaxf(gy, 0.0f), (float)(H_DIM - 1));
            int   yl = (int)floorf(y);
            float ly = y - (float)yl;
            int   yh = min(yl + 1, H_DIM - 1);

            #pragma unroll
            for (int sx = 0; sx < SR; ++sx) {
                float gx = x1 + bin_w * (((float)(ow * SR + sx) + 0.5f) / (float)SR);
                bool  vx = (gx >= -1.0f) && (gx <= (float)W_DIM);
                float x  = fminf(fmaxf(gx, 0.0f), (float)(W_DIM - 1));
                int   xl = (int)floorf(x);
                float lx = x - (float)xl;
                int   xh = min(xl + 1, W_DIM - 1);

                const uint2 qll = *(const uint2*)(img + (size_t)(yl * W_DIM + xl) * C_DIM + cb);
                const uint2 qlh = *(const uint2*)(img + (size_t)(yl * W_DIM + xh) * C_DIM + cb);
                const uint2 qhl = *(const uint2*)(img + (size_t)(yh * W_DIM + xl) * C_DIM + cb);
                const uint2 qhh = *(const uint2*)(img + (size_t)(yh * W_DIM + xh) * C_DIM + cb);

                float wll = (1.0f - ly) * (1.0f - lx);
                float wlh = (1.0f - ly) * lx;
                float whl = ly * (1.0f - lx);
                float whh = ly * lx;

                if (vy && vx) {
                    #define ACC2(acc, q, w) { \
                        float lo = __uint_as_float((q) << 16); \
                        float hi = __uint_as_float((q) & 0xffff0000u); \
                        acc.x = fmaf((w), lo, acc.x); \
                        acc.y = fmaf((w), hi, acc.y); }
                    ACC2(a01, qll.x, wll) ACC2(a23, qll.y, wll)
                    ACC2(a01, qlh.x, wlh) ACC2(a23, qlh.y, wlh)
                    ACC2(a01, qhl.x, whl) ACC2(a23, qhl.y, whl)
                    ACC2(a01, qhh.x, whh) ACC2(a23, qhh.y, whh)
                    #undef ACC2
                }
            }
        }
        s_out[(cb + 0) * NBINS + bin] = a01.x * 0.25f;
        s_out[(cb + 1) * NBINS + bin] = a01.y * 0.25f;
        s_out[(cb + 2) * NBINS + bin] = a23.x * 0.25f;
        s_out[(cb + 3) * NBINS + bin] = a23.y * 0.25f;
    }
    __syncthreads();

    // coalesced nontemporal copy-out: 12544 floats = 3136 float4
    nfloat4* o4 = (nfloat4*)(out + (size_t)k * (C_DIM * NBINS));
    const nfloat4* s4 = (const nfloat4*)s_out;
    for (int i = threadIdx.x; i < (C_DIM * NBINS) / 4; i += 256)
        __builtin_nontemporal_store(s4[i], o4 + i);
}

// ---------------- fallback (round-0 baseline) if ws too small ---------------
__global__ __launch_bounds__(256) void roi_align_naive(
    const float* __restrict__ input, const float* __restrict__ rois,
    float* __restrict__ out, int K)
{
    int idx = blockIdx.x * blockDim.x + threadIdx.x;
    int total = K * C_DIM * OUT_H * OUT_W;
    if (idx >= total) return;
    int ow = idx % OUT_W;
    int oh = (idx / OUT_W) % OUT_H;
    int c  = (idx / (OUT_W * OUT_H)) % C_DIM;
    int k  = idx / (OUT_W * OUT_H * C_DIM);
    const float* r = rois + (size_t)k * 5;
    int   b  = (int)r[0];
    float x1 = r[1] * SPATIAL_SCALE, y1 = r[2] * SPATIAL_SCALE;
    float x2 = r[3] * SPATIAL_SCALE, y2 = r[4] * SPATIAL_SCALE;
    float roi_w = fmaxf(x2 - x1, 1.0f), roi_h = fmaxf(y2 - y1, 1.0f);
    float bin_h = roi_h / OUT_H, bin_w = roi_w / OUT_W;
    const float* inp = input + ((size_t)b * C_DIM + c) * HW;
    float acc = 0.0f;
    #pragma unroll
    for (int sy = 0; sy < SR; ++sy) {
        float gy = y1 + bin_h * (((float)(oh * SR + sy) + 0.5f) / SR);
        bool vy = (gy >= -1.0f) && (gy <= (float)H_DIM);
        float y = fminf(fmaxf(gy, 0.0f), (float)(H_DIM - 1));
        int yl = (int)floorf(y); float ly = y - yl; int yh = min(yl + 1, H_DIM - 1);
        #pragma unroll
        for (int sx = 0; sx < SR; ++sx) {
            float gx = x1 + bin_w * (((float)(ow * SR + sx) + 0.5f) / SR);
            bool vx = (gx >= -1.0f) && (gx <= (float)W_DIM);
            float x = fminf(fmaxf(gx, 0.0f), (float)(W_DIM - 1));
            int xl = (int)floorf(x); float lx = x - xl; int xh = min(xl + 1, W_DIM - 1);
            float v = (1.0f - ly) * ((1.0f - lx) * inp[yl * W_DIM + xl] + lx * inp[yl * W_DIM + xh])
                    + ly * ((1.0f - lx) * inp[yh * W_DIM + xl] + lx * inp[yh * W_DIM + xh]);
            if (vy && vx) acc += v;
        }
    }
    out[idx] = acc * 0.25f;
}

extern "C" void kernel_launch(void* const* d_in, const int* in_sizes, int n_in,
                              void* d_out, int out_size, void* d_ws, size_t ws_size,
                              hipStream_t stream) {
    const float* input = (const float*)d_in[0];
    const float* rois  = (const float*)d_in[1];
    float* out = (float*)d_out;
    int K = in_sizes[1] / 5;

    if (ws_size >= NHWC_BF16_BYTES + (size_t)K * sizeof(int) && K <= MAX_BUCKET_K) {
        unsigned short* nhwc = (unsigned short*)d_ws;
        int* map = (int*)((char*)d_ws + NHWC_BF16_BYTES);
        dim3 tgrid((HW + 63) / 64, C_DIM / 64, N_DIM);   // 157 x 4 x 8
        nchw_to_nhwc_bf16<<<tgrid, 256, 0, stream>>>(input, nhwc);
        bucket_by_batch<<<1, 1024, 0, stream>>>(rois, K, map);
        roi_gather_nhwc_bf16<<<K, 256, 0, stream>>>(nhwc, rois, map, out, K);
    } else if (ws_size >= NHWC_BF16_BYTES) {
        unsigned short* nhwc = (unsigned short*)d_ws;
        dim3 tgrid((HW + 63) / 64, C_DIM / 64, N_DIM);
        nchw_to_nhwc_bf16<<<tgrid, 256, 0, stream>>>(input, nhwc);
        roi_gather_nhwc_bf16<<<K, 256, 0, stream>>>(nhwc, rois, nullptr, out, K);
    } else {
        int total = K * C_DIM * OUT_H * OUT_W;
        roi_align_naive<<<(total + 255) / 256, 256, 0, stream>>>(input, rois, out, K);
    }
}

// Round 9
// 168.734 us; speedup vs baseline: 1.1284x; 1.0881x over previous
//
#include <hip/hip_runtime.h>

// ROI Align on MI355X.
// input: (N=8, C=256, H=100, W=100) fp32 NCHW; rois (K,5); out (K,256,7,7) fp32.
//
// Round 9: r8 (batch->XCD affinity) cut FETCH 98->26MB but gather only 62->52us:
// limiter is L2-request concurrency (784 loads/ROI, ~6 effective waves/CU).
// Restructure: corner-quadrant scheme. Block = (ROI via map, 128-ch half);
// wave = bin; lane = q*16+c (q = bilinear corner, c = 8 bf16 channels).
// One uint4 load per sample fetches all 4 corners across the wave (4 loads/bin
// vs 16), shfl_xor(16/32) reduces corners. 25KB LDS -> 6 blk/CU, 2000 blocks.

typedef float nfloat4 __attribute__((ext_vector_type(4)));

constexpr int   OUT_H = 7;
constexpr int   OUT_W = 7;
constexpr int   NBINS = OUT_H * OUT_W;          // 49
constexpr float SPATIAL_SCALE = 0.25f;
constexpr int   SR = 2;
constexpr int   N_DIM = 8;
constexpr int   C_DIM = 256;
constexpr int   H_DIM = 100;
constexpr int   W_DIM = 100;
constexpr int   HW    = H_DIM * W_DIM;          // 10000
constexpr size_t NHWC_BF16_BYTES = (size_t)N_DIM * HW * C_DIM * 2; // 40,960,000
constexpr int   MAX_BUCKET_K = 2048;

__device__ inline unsigned short f2bf_rne(float f) {
    unsigned u = __float_as_uint(f);
    u += 0x7fffu + ((u >> 16) & 1u);    // round-to-nearest-even
    return (unsigned short)(u >> 16);
}

// ---------------- transpose+cast: NCHW fp32 -> NHWC bf16 (unchanged r6) -----
constexpr int TP = 65;

__global__ __launch_bounds__(256) void nchw_to_nhwc_bf16(
    const float* __restrict__ in, unsigned short* __restrict__ out)
{
    __shared__ float tile[64 * TP];    // 16640 B
    int s0 = blockIdx.x * 64;
    int c0 = blockIdx.y * 64;
    int n  = blockIdx.z;

    int t   = threadIdx.x;
    int sl4 = (t & 15) * 4;
    int cq  = t >> 4;                  // 0..15

    #pragma unroll
    for (int r = 0; r < 4; ++r) {
        int cl = r * 16 + cq;
        int s  = s0 + sl4;
        const float* src = in + ((size_t)(n * C_DIM + c0 + cl) * HW + s);
        if (s + 3 < HW) {
            float4 v = *(const float4*)src;
            tile[cl * TP + sl4 + 0] = v.x;
            tile[cl * TP + sl4 + 1] = v.y;
            tile[cl * TP + sl4 + 2] = v.z;
            tile[cl * TP + sl4 + 3] = v.w;
        } else {
            #pragma unroll
            for (int i = 0; i < 4; ++i)
                tile[cl * TP + sl4 + i] = (s + i < HW) ? src[i] : 0.0f;
        }
    }
    __syncthreads();

    int cl4 = (t & 15) * 4;
    #pragma unroll
    for (int r = 0; r < 4; ++r) {
        int sl = r * 16 + cq;
        int s  = s0 + sl;
        if (s < HW) {
            ushort4 h;
            h.x = f2bf_rne(tile[(cl4 + 0) * TP + sl]);
            h.y = f2bf_rne(tile[(cl4 + 1) * TP + sl]);
            h.z = f2bf_rne(tile[(cl4 + 2) * TP + sl]);
            h.w = f2bf_rne(tile[(cl4 + 3) * TP + sl]);
            *(ushort4*)(out + ((size_t)n * HW + s) * C_DIM + c0 + cl4) = h;
        }
    }
}

// ---------------- bucket: map[k] = ROI index with batch ~= k%8 (r8) ---------
__global__ __launch_bounds__(1024) void bucket_by_batch(
    const float* __restrict__ rois, int K, int* __restrict__ map)
{
    __shared__ int cnt[8];
    __shared__ int ovf[MAX_BUCKET_K];
    __shared__ int holes[MAX_BUCKET_K];
    __shared__ int ovfCnt, holeCnt;
    int t = threadIdx.x;
    if (t < 8) cnt[t] = 0;
    if (t == 0) { ovfCnt = 0; holeCnt = 0; }
    for (int i = t; i < K; i += 1024) map[i] = -1;
    __syncthreads();

    int per = K / 8;
    for (int i = t; i < K; i += 1024) {
        int b = ((int)rois[(size_t)i * 5]) & 7;
        int r = atomicAdd(&cnt[b], 1);
        if (r < per) map[b + 8 * r] = i;
        else ovf[atomicAdd(&ovfCnt, 1)] = i;
    }
    __syncthreads();
    for (int i = t; i < K; i += 1024)
        if (map[i] == -1) holes[atomicAdd(&holeCnt, 1)] = i;
    __syncthreads();
    for (int i = t; i < ovfCnt; i += 1024)
        map[holes[i]] = ovf[i];
}

// ---------------- gather: corner-quadrant, block=(ROI,ch-half), wave=bin ----
__global__ __launch_bounds__(256) void roi_gather_q(
    const unsigned short* __restrict__ nhwc,
    const float* __restrict__ rois,
    const int* __restrict__ map,
    float* __restrict__ out, int K)
{
    __shared__ float s_out[128 * NBINS];   // 25088 B

    int k = map ? map[blockIdx.x] : (int)blockIdx.x;
    int h = blockIdx.y;                    // channel half
    const float* r = rois + (size_t)k * 5;
    int   b  = (int)r[0];
    float x1 = r[1] * SPATIAL_SCALE;
    float y1 = r[2] * SPATIAL_SCALE;
    float x2 = r[3] * SPATIAL_SCALE;
    float y2 = r[4] * SPATIAL_SCALE;
    float roi_w = fmaxf(x2 - x1, 1.0f);
    float roi_h = fmaxf(y2 - y1, 1.0f);
    float bin_h = roi_h / (float)OUT_H;
    float bin_w = roi_w / (float)OUT_W;

    int wave = threadIdx.x >> 6;
    int lane = threadIdx.x & 63;
    int q    = lane >> 4;                  // corner: 0=ll 1=lh 2=hl 3=hh
    int c    = lane & 15;                  // 8-channel group within half
    int qy   = q >> 1;
    int qx   = q & 1;

    // lane's base: batch image + half + its 8 channels
    const unsigned short* img = nhwc + (size_t)b * HW * C_DIM + h * 128 + c * 8;

    for (int bin = wave; bin < NBINS; bin += 4) {
        int oh = bin / OUT_W;
        int ow = bin - oh * OUT_W;

        float acc[8] = {0.f, 0.f, 0.f, 0.f, 0.f, 0.f, 0.f, 0.f};

        #pragma unroll
        for (int sy = 0; sy < SR; ++sy) {
            float gy = y1 + bin_h * (((float)(oh * SR + sy) + 0.5f) / (float)SR);
            bool  vy = (gy >= -1.0f) && (gy <= (float)H_DIM);
            float y  = fminf(fmaxf(gy, 0.0f), (float)(H_DIM - 1));
            int   yl = (int)floorf(y);
            float ly = y - (float)yl;
            int   yh = min(yl + 1, H_DIM - 1);

            #pragma unroll
            for (int sx = 0; sx < SR; ++sx) {
                float gx = x1 + bin_w * (((float)(ow * SR + sx) + 0.5f) / (float)SR);
                bool  vx = (gx >= -1.0f) && (gx <= (float)W_DIM);
                float x  = fminf(fmaxf(gx, 0.0f), (float)(W_DIM - 1));
                int   xl = (int)floorf(x);
                float lx = x - (float)xl;
                int   xh = min(xl + 1, W_DIM - 1);

                int yy = qy ? yh : yl;
                int xx = qx ? xh : xl;
                float wy = qy ? ly : (1.0f - ly);
                float wx = qx ? lx : (1.0f - lx);
                float w  = (vy && vx) ? (wy * wx) : 0.0f;

                const uint4 v = *(const uint4*)(img + (size_t)(yy * W_DIM + xx) * C_DIM);

                #define ACCP(j, u) { \
                    acc[2*(j)+0] = fmaf(w, __uint_as_float((u) << 16),          acc[2*(j)+0]); \
                    acc[2*(j)+1] = fmaf(w, __uint_as_float((u) & 0xffff0000u),  acc[2*(j)+1]); }
                ACCP(0, v.x) ACCP(1, v.y) ACCP(2, v.z) ACCP(3, v.w)
                #undef ACCP
            }
        }

        // reduce the 4 corners: lanes {c, c+16, c+32, c+48} hold partials
        #pragma unroll
        for (int j = 0; j < 8; ++j) {
            acc[j] += __shfl_xor(acc[j], 16);
            acc[j] += __shfl_xor(acc[j], 32);
        }
        if (q == 0) {
            #pragma unroll
            for (int j = 0; j < 8; ++j)
                s_out[(c * 8 + j) * NBINS + bin] = acc[j] * 0.25f;
        }
    }
    __syncthreads();

    // coalesced nontemporal copy-out: 6272 floats = 1568 float4, contiguous
    nfloat4* o4 = (nfloat4*)(out + (size_t)k * (C_DIM * NBINS) + (size_t)h * 128 * NBINS);
    const nfloat4* s4 = (const nfloat4*)s_out;
    for (int i = threadIdx.x; i < (128 * NBINS) / 4; i += 256)
        __builtin_nontemporal_store(s4[i], o4 + i);
}

// ---------------- fallback (round-0 baseline) if ws too small ---------------
__global__ __launch_bounds__(256) void roi_align_naive(
    const float* __restrict__ input, const float* __restrict__ rois,
    float* __restrict__ out, int K)
{
    int idx = blockIdx.x * blockDim.x + threadIdx.x;
    int total = K * C_DIM * OUT_H * OUT_W;
    if (idx >= total) return;
    int ow = idx % OUT_W;
    int oh = (idx / OUT_W) % OUT_H;
    int c  = (idx / (OUT_W * OUT_H)) % C_DIM;
    int k  = idx / (OUT_W * OUT_H * C_DIM);
    const float* r = rois + (size_t)k * 5;
    int   b  = (int)r[0];
    float x1 = r[1] * SPATIAL_SCALE, y1 = r[2] * SPATIAL_SCALE;
    float x2 = r[3] * SPATIAL_SCALE, y2 = r[4] * SPATIAL_SCALE;
    float roi_w = fmaxf(x2 - x1, 1.0f), roi_h = fmaxf(y2 - y1, 1.0f);
    float bin_h = roi_h / OUT_H, bin_w = roi_w / OUT_W;
    const float* inp = input + ((size_t)b * C_DIM + c) * HW;
    float acc = 0.0f;
    #pragma unroll
    for (int sy = 0; sy < SR; ++sy) {
        float gy = y1 + bin_h * (((float)(oh * SR + sy) + 0.5f) / SR);
        bool vy = (gy >= -1.0f) && (gy <= (float)H_DIM);
        float y = fminf(fmaxf(gy, 0.0f), (float)(H_DIM - 1));
        int yl = (int)floorf(y); float ly = y - yl; int yh = min(yl + 1, H_DIM - 1);
        #pragma unroll
        for (int sx = 0; sx < SR; ++sx) {
            float gx = x1 + bin_w * (((float)(ow * SR + sx) + 0.5f) / SR);
            bool vx = (gx >= -1.0f) && (gx <= (float)W_DIM);
            float x = fminf(fmaxf(gx, 0.0f), (float)(W_DIM - 1));
            int xl = (int)floorf(x); float lx = x - xl; int xh = min(xl + 1, W_DIM - 1);
            float v = (1.0f - ly) * ((1.0f - lx) * inp[yl * W_DIM + xl] + lx * inp[yl * W_DIM + xh])
                    + ly * ((1.0f - lx) * inp[yh * W_DIM + xl] + lx * inp[yh * W_DIM + xh]);
            if (vy && vx) acc += v;
        }
    }
    out[idx] = acc * 0.25f;
}

extern "C" void kernel_launch(void* const* d_in, const int* in_sizes, int n_in,
                              void* d_out, int out_size, void* d_ws, size_t ws_size,
                              hipStream_t stream) {
    const float* input = (const float*)d_in[0];
    const float* rois  = (const float*)d_in[1];
    float* out = (float*)d_out;
    int K = in_sizes[1] / 5;

    if (ws_size >= NHWC_BF16_BYTES + (size_t)K * sizeof(int) && K <= MAX_BUCKET_K) {
        unsigned short* nhwc = (unsigned short*)d_ws;
        int* map = (int*)((char*)d_ws + NHWC_BF16_BYTES);
        dim3 tgrid((HW + 63) / 64, C_DIM / 64, N_DIM);   // 157 x 4 x 8
        nchw_to_nhwc_bf16<<<tgrid, 256, 0, stream>>>(input, nhwc);
        bucket_by_batch<<<1, 1024, 0, stream>>>(rois, K, map);
        dim3 ggrid(K, 2);
        roi_gather_q<<<ggrid, 256, 0, stream>>>(nhwc, rois, map, out, K);
    } else if (ws_size >= NHWC_BF16_BYTES) {
        unsigned short* nhwc = (unsigned short*)d_ws;
        dim3 tgrid((HW + 63) / 64, C_DIM / 64, N_DIM);
        nchw_to_nhwc_bf16<<<tgrid, 256, 0, stream>>>(input, nhwc);
        dim3 ggrid(K, 2);
        roi_gather_q<<<ggrid, 256, 0, stream>>>(nhwc, rois, nullptr, out, K);
    } else {
        int total = K * C_DIM * OUT_H * OUT_W;
        roi_align_naive<<<(total + 255) / 256, 256, 0, stream>>>(input, rois, out, K);
    }
}

// Round 10
// 165.505 us; speedup vs baseline: 1.1504x; 1.0195x over previous
//
#include <hip/hip_runtime.h>

// ROI Align on MI355X.
// input: (N=8, C=256, H=100, W=100) fp32 NCHW; rois (K,5); out (K,256,7,7) fp32.
//
// Round 10: r9 gather is VALU-bound (~194 ops/bin/lane, geometry ~70 of them
// recomputed identically by every lane). Precompute 14 x / 14 y sample geoms
// once per block into LDS ({lo,hi,l*v,(1-l)*v}, validity premultiplied);
// inner loop = 2 broadcast ds_read_b128 + selects + 1 uint4 corner-quadrant
// load + 8 fma. Bucket kernel folded into transpose launch (grid.x+1).

typedef float nfloat4 __attribute__((ext_vector_type(4)));

constexpr int   OUT_H = 7;
constexpr int   OUT_W = 7;
constexpr int   NBINS = OUT_H * OUT_W;          // 49
constexpr float SPATIAL_SCALE = 0.25f;
constexpr int   SR = 2;
constexpr int   N_DIM = 8;
constexpr int   C_DIM = 256;
constexpr int   H_DIM = 100;
constexpr int   W_DIM = 100;
constexpr int   HW    = H_DIM * W_DIM;          // 10000
constexpr size_t NHWC_BF16_BYTES = (size_t)N_DIM * HW * C_DIM * 2; // 40,960,000
constexpr int   MAX_BUCKET_K = 2048;

__device__ inline unsigned short f2bf_rne(float f) {
    unsigned u = __float_as_uint(f);
    u += 0x7fffu + ((u >> 16) & 1u);    // round-to-nearest-even
    return (unsigned short)(u >> 16);
}

// ---------------- transpose+cast + bucket (fused) ---------------------------
// blocks x<157: NCHW fp32 -> NHWC bf16, 64ch x 64sp tile, LDS stride 65.
// block (157,0,0): bucket -> map[k] = ROI index with batch ~= k%8.
constexpr int TP = 65;

union TransposeSh {
    float tile[64 * TP];                                   // 16640 B
    struct {
        int cnt[8]; int ovfCnt; int holeCnt;
        int ovf[MAX_BUCKET_K]; int holes[MAX_BUCKET_K];    // 16424 B
    } bk;
};

__global__ __launch_bounds__(256) void nchw_to_nhwc_bf16(
    const float* __restrict__ in, unsigned short* __restrict__ out,
    const float* __restrict__ rois, int K, int* __restrict__ map)
{
    __shared__ TransposeSh sh;
    int bx = blockIdx.x;
    int t  = threadIdx.x;

    if (bx == (HW + 63) / 64) {
        // ---- bucket branch: one block does the batch->position map ----
        if (blockIdx.y != 0 || blockIdx.z != 0 || map == nullptr) return;
        if (t < 8) sh.bk.cnt[t] = 0;
        if (t == 0) { sh.bk.ovfCnt = 0; sh.bk.holeCnt = 0; }
        for (int i = t; i < K; i += 256) map[i] = -1;
        __syncthreads();
        int per = K / 8;
        for (int i = t; i < K; i += 256) {
            int b = ((int)rois[(size_t)i * 5]) & 7;
            int r = atomicAdd(&sh.bk.cnt[b], 1);
            if (r < per) map[b + 8 * r] = i;
            else sh.bk.ovf[atomicAdd(&sh.bk.ovfCnt, 1)] = i;
        }
        __syncthreads();
        for (int i = t; i < K; i += 256)
            if (map[i] == -1) sh.bk.holes[atomicAdd(&sh.bk.holeCnt, 1)] = i;
        __syncthreads();
        for (int i = t; i < sh.bk.ovfCnt; i += 256)
            map[sh.bk.holes[i]] = sh.bk.ovf[i];
        return;
    }

    // ---- transpose branch ----
    int s0 = bx * 64;
    int c0 = blockIdx.y * 64;
    int n  = blockIdx.z;

    int sl4 = (t & 15) * 4;
    int cq  = t >> 4;                  // 0..15

    #pragma unroll
    for (int r = 0; r < 4; ++r) {
        int cl = r * 16 + cq;
        int s  = s0 + sl4;
        const float* src = in + ((size_t)(n * C_DIM + c0 + cl) * HW + s);
        if (s + 3 < HW) {
            float4 v = *(const float4*)src;
            sh.tile[cl * TP + sl4 + 0] = v.x;
            sh.tile[cl * TP + sl4 + 1] = v.y;
            sh.tile[cl * TP + sl4 + 2] = v.z;
            sh.tile[cl * TP + sl4 + 3] = v.w;
        } else {
            #pragma unroll
            for (int i = 0; i < 4; ++i)
                sh.tile[cl * TP + sl4 + i] = (s + i < HW) ? src[i] : 0.0f;
        }
    }
    __syncthreads();

    int cl4 = (t & 15) * 4;
    #pragma unroll
    for (int r = 0; r < 4; ++r) {
        int sl = r * 16 + cq;
        int s  = s0 + sl;
        if (s < HW) {
            ushort4 h;
            h.x = f2bf_rne(sh.tile[(cl4 + 0) * TP + sl]);
            h.y = f2bf_rne(sh.tile[(cl4 + 1) * TP + sl]);
            h.z = f2bf_rne(sh.tile[(cl4 + 2) * TP + sl]);
            h.w = f2bf_rne(sh.tile[(cl4 + 3) * TP + sl]);
            *(ushort4*)(out + ((size_t)n * HW + s) * C_DIM + c0 + cl4) = h;
        }
    }
}

// ---------------- gather: corner-quadrant + LDS geometry --------------------
// block = (ROI via map, 128-ch half); wave = bin; lane = q*16+c.
// Geometry {lo, hi, l*v, (1-l)*v} for 14 x / 14 y sample positions computed
// once per block; inner loop is broadcast ds_read + selects + one uint4 load.
struct alignas(16) Geom { int lo; int hi; float wv; float mwv; };

__global__ __launch_bounds__(256) void roi_gather_q(
    const unsigned short* __restrict__ nhwc,
    const float* __restrict__ rois,
    const int* __restrict__ map,
    float* __restrict__ out, int K)
{
    __shared__ float s_out[128 * NBINS];   // 25088 B
    __shared__ Geom xg[OUT_W * SR];        // 14
    __shared__ Geom yg[OUT_H * SR];        // 14

    int k = map ? map[blockIdx.x] : (int)blockIdx.x;
    int h = blockIdx.y;                    // channel half
    const float* r = rois + (size_t)k * 5;
    int   b  = (int)r[0];
    float x1 = r[1] * SPATIAL_SCALE;
    float y1 = r[2] * SPATIAL_SCALE;
    float x2 = r[3] * SPATIAL_SCALE;
    float y2 = r[4] * SPATIAL_SCALE;
    float roi_w = fmaxf(x2 - x1, 1.0f);
    float roi_h = fmaxf(y2 - y1, 1.0f);
    float bin_h = roi_h / (float)OUT_H;
    float bin_w = roi_w / (float)OUT_W;

    int t = threadIdx.x;
    // fill geometry: threads 0..13 -> x, 64..77 -> y (separate waves)
    if (t < OUT_W * SR) {
        float g = x1 + bin_w * (((float)t + 0.5f) * 0.5f);
        float v = (g >= -1.0f && g <= (float)W_DIM) ? 1.0f : 0.0f;
        float x = fminf(fmaxf(g, 0.0f), (float)(W_DIM - 1));
        int   lo = (int)floorf(x);
        float l  = x - (float)lo;
        xg[t].lo = lo; xg[t].hi = min(lo + 1, W_DIM - 1);
        xg[t].wv = l * v; xg[t].mwv = (1.0f - l) * v;
    } else if (t >= 64 && t < 64 + OUT_H * SR) {
        int i = t - 64;
        float g = y1 + bin_h * (((float)i + 0.5f) * 0.5f);
        float v = (g >= -1.0f && g <= (float)H_DIM) ? 1.0f : 0.0f;
        float y = fminf(fmaxf(g, 0.0f), (float)(H_DIM - 1));
        int   lo = (int)floorf(y);
        float l  = y - (float)lo;
        yg[i].lo = lo; yg[i].hi = min(lo + 1, H_DIM - 1);
        yg[i].wv = l * v; yg[i].mwv = (1.0f - l) * v;
    }
    __syncthreads();

    int wave = t >> 6;
    int lane = t & 63;
    int q    = lane >> 4;                  // corner: 0=ll 1=lh 2=hl 3=hh
    int c    = lane & 15;                  // 8-channel group within half
    int qy   = q >> 1;
    int qx   = q & 1;

    const unsigned short* img = nhwc + (size_t)b * HW * C_DIM + h * 128 + c * 8;

    for (int bin = wave; bin < NBINS; bin += 4) {
        int oh = bin / OUT_W;
        int ow = bin - oh * OUT_W;

        float acc[8] = {0.f, 0.f, 0.f, 0.f, 0.f, 0.f, 0.f, 0.f};

        #pragma unroll
        for (int sy = 0; sy < SR; ++sy) {
            Geom gy = yg[oh * SR + sy];
            int   yy = qy ? gy.hi : gy.lo;
            float wy = qy ? gy.wv : gy.mwv;

            #pragma unroll
            for (int sx = 0; sx < SR; ++sx) {
                Geom gx = xg[ow * SR + sx];
                int   xx = qx ? gx.hi : gx.lo;
                float wx = qx ? gx.wv : gx.mwv;
                float w  = wy * wx;

                const uint4 v = *(const uint4*)(img + (size_t)(yy * W_DIM + xx) * C_DIM);

                #define ACCP(j, u) { \
                    acc[2*(j)+0] = fmaf(w, __uint_as_float((u) << 16),          acc[2*(j)+0]); \
                    acc[2*(j)+1] = fmaf(w, __uint_as_float((u) & 0xffff0000u),  acc[2*(j)+1]); }
                ACCP(0, v.x) ACCP(1, v.y) ACCP(2, v.z) ACCP(3, v.w)
                #undef ACCP
            }
        }

        // reduce the 4 corners: lanes {c, c+16, c+32, c+48} hold partials
        #pragma unroll
        for (int j = 0; j < 8; ++j) {
            acc[j] += __shfl_xor(acc[j], 16);
            acc[j] += __shfl_xor(acc[j], 32);
        }
        if (q == 0) {
            #pragma unroll
            for (int j = 0; j < 8; ++j)
                s_out[(c * 8 + j) * NBINS + bin] = acc[j] * 0.25f;
        }
    }
    __syncthreads();

    // coalesced nontemporal copy-out: 6272 floats = 1568 float4, contiguous
    nfloat4* o4 = (nfloat4*)(out + (size_t)k * (C_DIM * NBINS) + (size_t)h * 128 * NBINS);
    const nfloat4* s4 = (const nfloat4*)s_out;
    for (int i = t; i < (128 * NBINS) / 4; i += 256)
        __builtin_nontemporal_store(s4[i], o4 + i);
}

// ---------------- fallback (round-0 baseline) if ws too small ---------------
__global__ __launch_bounds__(256) void roi_align_naive(
    const float* __restrict__ input, const float* __restrict__ rois,
    float* __restrict__ out, int K)
{
    int idx = blockIdx.x * blockDim.x + threadIdx.x;
    int total = K * C_DIM * OUT_H * OUT_W;
    if (idx >= total) return;
    int ow = idx % OUT_W;
    int oh = (idx / OUT_W) % OUT_H;
    int c  = (idx / (OUT_W * OUT_H)) % C_DIM;
    int k  = idx / (OUT_W * OUT_H * C_DIM);
    const float* r = rois + (size_t)k * 5;
    int   b  = (int)r[0];
    float x1 = r[1] * SPATIAL_SCALE, y1 = r[2] * SPATIAL_SCALE;
    float x2 = r[3] * SPATIAL_SCALE, y2 = r[4] * SPATIAL_SCALE;
    float roi_w = fmaxf(x2 - x1, 1.0f), roi_h = fmaxf(y2 - y1, 1.0f);
    float bin_h = roi_h / OUT_H, bin_w = roi_w / OUT_W;
    const float* inp = input + ((size_t)b * C_DIM + c) * HW;
    float acc = 0.0f;
    #pragma unroll
    for (int sy = 0; sy < SR; ++sy) {
        float gy = y1 + bin_h * (((float)(oh * SR + sy) + 0.5f) / SR);
        bool vy = (gy >= -1.0f) && (gy <= (float)H_DIM);
        float y = fminf(fmaxf(gy, 0.0f), (float)(H_DIM - 1));
        int yl = (int)floorf(y); float ly = y - yl; int yh = min(yl + 1, H_DIM - 1);
        #pragma unroll
        for (int sx = 0; sx < SR; ++sx) {
            float gx = x1 + bin_w * (((float)(ow * SR + sx) + 0.5f) / SR);
            bool vx = (gx >= -1.0f) && (gx <= (float)W_DIM);
            float x = fminf(fmaxf(gx, 0.0f), (float)(W_DIM - 1));
            int xl = (int)floorf(x); float lx = x - xl; int xh = min(xl + 1, W_DIM - 1);
            float v = (1.0f - ly) * ((1.0f - lx) * inp[yl * W_DIM + xl] + lx * inp[yl * W_DIM + xh])
                    + ly * ((1.0f - lx) * inp[yh * W_DIM + xl] + lx * inp[yh * W_DIM + xh]);
            if (vy && vx) acc += v;
        }
    }
    out[idx] = acc * 0.25f;
}

extern "C" void kernel_launch(void* const* d_in, const int* in_sizes, int n_in,
                              void* d_out, int out_size, void* d_ws, size_t ws_size,
                              hipStream_t stream) {
    const float* input = (const float*)d_in[0];
    const float* rois  = (const float*)d_in[1];
    float* out = (float*)d_out;
    int K = in_sizes[1] / 5;
    int ntiles = (HW + 63) / 64;    // 157

    if (ws_size >= NHWC_BF16_BYTES + (size_t)K * sizeof(int) && K <= MAX_BUCKET_K) {
        unsigned short* nhwc = (unsigned short*)d_ws;
        int* map = (int*)((char*)d_ws + NHWC_BF16_BYTES);
        dim3 tgrid(ntiles + 1, C_DIM / 64, N_DIM);   // 158 x 4 x 8 (+1 = bucket block)
        nchw_to_nhwc_bf16<<<tgrid, 256, 0, stream>>>(input, nhwc, rois, K, map);
        dim3 ggrid(K, 2);
        roi_gather_q<<<ggrid, 256, 0, stream>>>(nhwc, rois, map, out, K);
    } else if (ws_size >= NHWC_BF16_BYTES) {
        unsigned short* nhwc = (unsigned short*)d_ws;
        dim3 tgrid(ntiles, C_DIM / 64, N_DIM);
        nchw_to_nhwc_bf16<<<tgrid, 256, 0, stream>>>(input, nhwc, rois, K, nullptr);
        dim3 ggrid(K, 2);
        roi_gather_q<<<ggrid, 256, 0, stream>>>(nhwc, rois, nullptr, out, K);
    } else {
        int total = K * C_DIM * OUT_H * OUT_W;
        roi_align_naive<<<(total + 255) / 256, 256, 0, stream>>>(input, rois, out, K);
    }
}